// Round 4
// baseline (104.897 us; speedup 1.0000x reference)
//
#include <hip/hip_runtime.h>
#include <stdint.h>

#define T_TOKENS 8192
#define K_DIM    4096
#define NEXP     64
#define TB       128            // tokens per gemm block (8 waves x 16)
#define KC       32             // k per chunk = one MFMA k-step

typedef short bf16x8 __attribute__((ext_vector_type(8)));
typedef float f32x4  __attribute__((ext_vector_type(4)));

// float -> bf16 (RNE) bit tricks; residual v - bf2f(f2bf(v)) is exact in fp32
__device__ __forceinline__ uint32_t f2bf(float v) {
    uint32_t u = __builtin_bit_cast(uint32_t, v);
    return (u + 0x7fffu + ((u >> 16) & 1u)) >> 16;
}
__device__ __forceinline__ float bf2f(uint32_t b) {
    return __builtin_bit_cast(float, b << 16);
}

// ---------- kernel 0: W [64][4096] fp32 -> fragment-ordered bf16 terms -------
// Wf layout (float4 = bf16x8 units): [kstep 128][etile 4][term 3][lane 64]
// B-frag content: lane l, elem j = W[etile*16 + (l&15)][kstep*32 + (l>>4)*8 + j]
__global__ void wpack(const float* __restrict__ W, float4* __restrict__ Wf) {
    const int l     = threadIdx.x;       // 0..63
    const int kstep = blockIdx.x;        // 0..127
    const int etile = blockIdx.y;        // 0..3
    const int e = etile * 16 + (l & 15);
    const int k = kstep * 32 + (l >> 4) * 8;
    const float* src = W + (size_t)e * K_DIM + k;
    bf16x8 h, l1, l2;
#pragma unroll
    for (int j = 0; j < 8; ++j) {
        float v = src[j];
        uint32_t hb = f2bf(v); float r  = v - bf2f(hb);
        uint32_t lb = f2bf(r); float r2 = r - bf2f(lb);
        uint32_t qb = f2bf(r2);
        h[j] = (short)hb; l1[j] = (short)lb; l2[j] = (short)qb;
    }
    const size_t base = ((size_t)(kstep * 4 + etile) * 3) * 64 + l;
    Wf[base]       = __builtin_bit_cast(float4, h);
    Wf[base + 64]  = __builtin_bit_cast(float4, l1);
    Wf[base + 128] = __builtin_bit_cast(float4, l2);
}

// ---------- kernel 1: split-K GEMM, logits partials via 6x bf16 MFMA ---------
// B fragments read DIRECTLY from Wf (L2-resident, per-lane pre-ordered) — no
// LDS staging for B. LDS holds only the x tile (32 KB double-buffered,
// XOR-swizzled, conflict-free b128 on both sides). ONE barrier per chunk.
__global__ __launch_bounds__(512, 4) void gemm_mfma(
    const float*  __restrict__ x,
    const float4* __restrict__ Wf,
    float* __restrict__ P,          // [S][8192][64]
    int KS)                         // k per slice
{
    __shared__ float4 xbuf[2][TB * 8];   // 128 rows x 8 f4 (XOR-swz) x2 = 32 KB

    const int tid  = threadIdx.x;
    const int l    = tid & 63;
    const int wv   = __builtin_amdgcn_readfirstlane(tid >> 6);  // token-16 tile
    const int t0   = blockIdx.x * TB;
    const int slice = blockIdx.y;
    const int k0   = slice * KS;
    const int nchunk = KS / KC;

    // x staging role: thread covers rows {tid>>3, tid>>3+64}, f4-slot tid&7
    const int srow  = tid >> 3;
    const int sslot = tid & 7;
    const float4* x4 = (const float4*)x;
    const size_t xg0 = (size_t)(t0 + srow) * (K_DIM / 4) + (size_t)(k0 >> 2) + sslot;
    const size_t xg1 = xg0 + (size_t)64 * (K_DIM / 4);

    f32x4 acc[4];
#pragma unroll
    for (int et = 0; et < 4; ++et) acc[et] = (f32x4){0.f, 0.f, 0.f, 0.f};

    // prologue: stage x chunk 0 into regs
    float4 xr0 = x4[xg0];
    float4 xr1 = x4[xg1];

    // A-read address (swizzled): row = wv*16 + (l&15), slots (l>>4)*2, +1
    const int arow = wv * 16 + (l & 15);
    const int as0 = arow * 8 + (((l >> 4) * 2)     ^ (arow & 7));
    const int as1 = arow * 8 + (((l >> 4) * 2 + 1) ^ (arow & 7));

    for (int c = 0; c < nchunk; ++c) {
        const int b = c & 1;
        // commit staged x chunk c (conflict-free swizzled b128 writes)
        xbuf[b][srow * 8        + (sslot ^ (srow & 7))]        = xr0;
        xbuf[b][(srow + 64) * 8 + (sslot ^ ((srow + 64) & 7))] = xr1;
        __syncthreads();   // the only barrier: WAR on buf b is 2 barriers out

        // prefetch x chunk c+1 (consumed at next commit)
        if (c + 1 < nchunk) {
            xr0 = x4[xg0 + (size_t)(c + 1) * 8];
            xr1 = x4[xg1 + (size_t)(c + 1) * 8];
        }

        // B fragments for chunk c straight from L2 (per-lane pre-ordered)
        const int kstep = (k0 >> 5) + c;
        const float4* bp = Wf + ((size_t)(kstep * 4) * 3) * 64 + l;
        float4 breg[12];
#pragma unroll
        for (int q = 0; q < 12; ++q)
            breg[q] = bp[q * 64];

        // A fragments: 8 fp32 -> 3 bf16 terms (covers B's L2 latency)
        float4 a0 = xbuf[b][as0];
        float4 a1 = xbuf[b][as1];
        float av[8] = {a0.x, a0.y, a0.z, a0.w, a1.x, a1.y, a1.z, a1.w};
        bf16x8 xh, xl, xq;
#pragma unroll
        for (int j = 0; j < 8; ++j) {
            float v = av[j];
            uint32_t hb = f2bf(v); float r  = v - bf2f(hb);
            uint32_t lb = f2bf(r); float r2 = r - bf2f(lb);
            uint32_t qb = f2bf(r2);
            xh[j] = (short)hb; xl[j] = (short)lb; xq[j] = (short)qb;
        }

#pragma unroll
        for (int et = 0; et < 4; ++et) {
            bf16x8 wh = __builtin_bit_cast(bf16x8, breg[et * 3 + 0]);
            bf16x8 wl = __builtin_bit_cast(bf16x8, breg[et * 3 + 1]);
            bf16x8 wq = __builtin_bit_cast(bf16x8, breg[et * 3 + 2]);
            acc[et] = __builtin_amdgcn_mfma_f32_16x16x32_bf16(xh, wh, acc[et], 0, 0, 0);
            acc[et] = __builtin_amdgcn_mfma_f32_16x16x32_bf16(xh, wl, acc[et], 0, 0, 0);
            acc[et] = __builtin_amdgcn_mfma_f32_16x16x32_bf16(xh, wq, acc[et], 0, 0, 0);
            acc[et] = __builtin_amdgcn_mfma_f32_16x16x32_bf16(xl, wh, acc[et], 0, 0, 0);
            acc[et] = __builtin_amdgcn_mfma_f32_16x16x32_bf16(xl, wl, acc[et], 0, 0, 0);
            acc[et] = __builtin_amdgcn_mfma_f32_16x16x32_bf16(xq, wh, acc[et], 0, 0, 0);
        }
    }

    // epilogue: C/D map col=lane&15 (expert), row=(lane>>4)*4+i (token)
    float* Pp = P + (size_t)slice * T_TOKENS * NEXP;
#pragma unroll
    for (int et = 0; et < 4; ++et) {
#pragma unroll
        for (int i = 0; i < 4; ++i) {
            int t = t0 + wv * 16 + (l >> 4) * 4 + i;
            Pp[(size_t)t * NEXP + et * 16 + (l & 15)] = acc[et][i];
        }
    }
}

// ---------- kernel 2: reduce slices + softmax + argmax + bincount ------------
__global__ __launch_bounds__(256) void router_finish(
    const float* __restrict__ P, float* __restrict__ out, int S)
{
    const int lane = threadIdx.x & 63;   // expert
    const int wv   = threadIdx.x >> 6;
    const int t    = blockIdx.x * 4 + wv;

    float lg = 0.f;
    for (int s = 0; s < S; ++s)
        lg += P[((size_t)s * T_TOKENS + t) * NEXP + lane];

    float* out_w = out;
    float* out_i = out + T_TOKENS;
    float* out_s = out + 2 * T_TOKENS;
    float* out_c = out + 2 * T_TOKENS + (size_t)T_TOKENS * NEXP;

    float m = lg;
#pragma unroll
    for (int off = 32; off > 0; off >>= 1)
        m = fmaxf(m, __shfl_xor(m, off));
    float p = expf(lg - m);
    float s = p;
#pragma unroll
    for (int off = 32; off > 0; off >>= 1)
        s += __shfl_xor(s, off);
    float sc = p / s;

    float bv = sc; int bi = lane;
#pragma unroll
    for (int off = 32; off > 0; off >>= 1) {
        float ov = __shfl_xor(bv, off);
        int   oi = __shfl_xor(bi, off);
        if (ov > bv || (ov == bv && oi < bi)) { bv = ov; bi = oi; }
    }
    out_s[(size_t)t * NEXP + lane] = sc;
    if (lane == 0) {
        out_w[t] = bv;
        out_i[t] = (float)bi;
        atomicAdd(&out_c[bi], 1.0f);
    }
}

extern "C" void kernel_launch(void* const* d_in, const int* in_sizes, int n_in,
                              void* d_out, int out_size, void* d_ws, size_t ws_size,
                              hipStream_t stream)
{
    const float* x = (const float*)d_in[0];
    const float* W = (const float*)d_in[1];
    float* out = (float*)d_out;
    float* out_s = out + 2 * T_TOKENS;

    const size_t wf_bytes  = (size_t)128 * 4 * 3 * 64 * 16;           // 1.5 MiB
    const size_t per_slice = (size_t)T_TOKENS * NEXP * sizeof(float); // 2 MiB

    int S = 8;
    while (S > 1 && wf_bytes + (size_t)S * per_slice > ws_size) S >>= 1;
    float4* Wf = (float4*)d_ws;
    float* Pbuf;
    if (wf_bytes + per_slice <= ws_size) {
        Pbuf = (float*)((char*)d_ws + wf_bytes);
    } else {
        S = 1;
        Pbuf = out_s;   // single slice written straight into scores region
    }

    hipMemsetAsync(out + 2 * T_TOKENS + (size_t)T_TOKENS * NEXP, 0,
                   NEXP * sizeof(float), stream);

    wpack<<<dim3(128, 4), 64, 0, stream>>>(W, Wf);
    gemm_mfma<<<dim3(T_TOKENS / TB, S), 512, 0, stream>>>(x, Wf, Pbuf, K_DIM / S);
    router_finish<<<T_TOKENS / 4, 256, 0, stream>>>(Pbuf, out, S);
}

// Round 5
// 94.758 us; speedup vs baseline: 1.1070x; 1.1070x over previous
//
#include <hip/hip_runtime.h>
#include <stdint.h>

#define T_TOKENS 8192
#define K_DIM    4096
#define NEXP     64
#define TB       128            // tokens per gemm block (8 waves x 16)
#define KC       32             // k per chunk = one MFMA k-step

typedef short bf16x8 __attribute__((ext_vector_type(8)));
typedef float f32x4  __attribute__((ext_vector_type(4)));

// float -> bf16 (RNE) bit tricks; residual v - bf2f(f2bf(v)) is exact in fp32
__device__ __forceinline__ uint32_t f2bf(float v) {
    uint32_t u = __builtin_bit_cast(uint32_t, v);
    return (u + 0x7fffu + ((u >> 16) & 1u)) >> 16;
}
__device__ __forceinline__ float bf2f(uint32_t b) {
    return __builtin_bit_cast(float, b << 16);
}

// ---------- kernel 0: W [64][4096] fp32 -> fragment-ordered bf16 terms -------
// Wf layout (float4 = bf16x8 units): [kstep 128][etile 4][term 3][lane 64]
// B-frag content: lane l, elem j = W[etile*16 + (l&15)][kstep*32 + (l>>4)*8 + j]
// Block (0,0) also zeroes the routing-counts output (replaces graph memset).
__global__ void wpack(const float* __restrict__ W, float4* __restrict__ Wf,
                      float* __restrict__ out_counts) {
    const int l     = threadIdx.x;       // 0..63
    const int kstep = blockIdx.x;        // 0..127
    const int etile = blockIdx.y;        // 0..3
    if (kstep == 0 && etile == 0)
        out_counts[l] = 0.f;             // stream-ordered before router_finish
    const int e = etile * 16 + (l & 15);
    const int k = kstep * 32 + (l >> 4) * 8;
    const float* src = W + (size_t)e * K_DIM + k;
    bf16x8 h, l1, l2;
#pragma unroll
    for (int j = 0; j < 8; ++j) {
        float v = src[j];
        uint32_t hb = f2bf(v); float r  = v - bf2f(hb);
        uint32_t lb = f2bf(r); float r2 = r - bf2f(lb);
        uint32_t qb = f2bf(r2);
        h[j] = (short)hb; l1[j] = (short)lb; l2[j] = (short)qb;
    }
    const size_t base = ((size_t)(kstep * 4 + etile) * 3) * 64 + l;
    Wf[base]       = __builtin_bit_cast(float4, h);
    Wf[base + 64]  = __builtin_bit_cast(float4, l1);
    Wf[base + 128] = __builtin_bit_cast(float4, l2);
}

// ---------- kernel 1: split-K GEMM, logits partials via 6x bf16 MFMA ---------
// x tile: 32 KB LDS dbuf, XOR-swizzled, conflict-free b128 both sides.
// B tile: 24 KB LDS dbuf, linear (per-lane-ordered fragments), loaded from L2
// once per block per chunk. ONE barrier per chunk (dbuf WAR spans 2 barriers).
__global__ __launch_bounds__(512, 4) void gemm_mfma(
    const float*  __restrict__ x,
    const float4* __restrict__ Wf,
    float* __restrict__ P,          // [S][8192][64]
    int KS)                         // k per slice
{
    __shared__ float4 xbuf[2][TB * 8];   // 128 rows x 8 f4 (XOR-swz) x2 = 32 KB
    __shared__ float4 bbuf[2][12 * 64];  // [etile][term][lane] x2 = 24 KB

    const int tid  = threadIdx.x;
    const int l    = tid & 63;
    const int wv   = __builtin_amdgcn_readfirstlane(tid >> 6);  // token-16 tile
    const int t0   = blockIdx.x * TB;
    const int slice = blockIdx.y;
    const int k0   = slice * KS;
    const int nchunk = KS / KC;

    // x staging role: thread covers rows {tid>>3, tid>>3+64}, f4-slot tid&7
    const int srow  = tid >> 3;
    const int sslot = tid & 7;
    const float4* x4 = (const float4*)x;
    const size_t xg0 = (size_t)(t0 + srow) * (K_DIM / 4) + (size_t)(k0 >> 2) + sslot;
    const size_t xg1 = xg0 + (size_t)64 * (K_DIM / 4);
    // B staging: slot tid, plus slot tid+512 for tid<256 (768 f4 = 12 KB/chunk)
    const size_t bg0 = ((size_t)(k0 / 32)) * 768;

    f32x4 acc[4];
#pragma unroll
    for (int et = 0; et < 4; ++et) acc[et] = (f32x4){0.f, 0.f, 0.f, 0.f};

    // prologue: stage chunk 0 into regs
    float4 xr0 = x4[xg0];
    float4 xr1 = x4[xg1];
    float4 br0 = Wf[bg0 + tid];
    float4 br1 = (tid < 256) ? Wf[bg0 + tid + 512] : (float4){0, 0, 0, 0};

    // A-read address (swizzled): row = wv*16 + (l&15), slots (l>>4)*2, +1
    const int arow = wv * 16 + (l & 15);
    const int as0 = arow * 8 + (((l >> 4) * 2)     ^ (arow & 7));
    const int as1 = arow * 8 + (((l >> 4) * 2 + 1) ^ (arow & 7));

    for (int c = 0; c < nchunk; ++c) {
        const int b = c & 1;
        // commit staged chunk c (x swizzled, B linear) — conflict-free writes
        xbuf[b][srow * 8        + (sslot ^ (srow & 7))]        = xr0;
        xbuf[b][(srow + 64) * 8 + (sslot ^ ((srow + 64) & 7))] = xr1;
        bbuf[b][tid] = br0;
        if (tid < 256) bbuf[b][tid + 512] = br1;
        __syncthreads();   // only barrier: WAR on buf b is 2 barriers out

        // prefetch chunk c+1 (consumed at next commit)
        if (c + 1 < nchunk) {
            xr0 = x4[xg0 + (size_t)(c + 1) * 8];
            xr1 = x4[xg1 + (size_t)(c + 1) * 8];
            br0 = Wf[bg0 + (size_t)(c + 1) * 768 + tid];
            if (tid < 256) br1 = Wf[bg0 + (size_t)(c + 1) * 768 + tid + 512];
        }

        // A fragments: 8 fp32 -> 3 bf16 terms
        float4 a0 = xbuf[b][as0];
        float4 a1 = xbuf[b][as1];
        float av[8] = {a0.x, a0.y, a0.z, a0.w, a1.x, a1.y, a1.z, a1.w};
        bf16x8 xh, xl, xq;
#pragma unroll
        for (int j = 0; j < 8; ++j) {
            float v = av[j];
            uint32_t hb = f2bf(v); float r  = v - bf2f(hb);
            uint32_t lb = f2bf(r); float r2 = r - bf2f(lb);
            uint32_t qb = f2bf(r2);
            xh[j] = (short)hb; xl[j] = (short)lb; xq[j] = (short)qb;
        }

#pragma unroll
        for (int et = 0; et < 4; ++et) {
            const float4* bp = &bbuf[b][et * 3 * 64 + l];
            bf16x8 wh = __builtin_bit_cast(bf16x8, bp[0]);
            bf16x8 wl = __builtin_bit_cast(bf16x8, bp[64]);
            bf16x8 wq = __builtin_bit_cast(bf16x8, bp[128]);
            acc[et] = __builtin_amdgcn_mfma_f32_16x16x32_bf16(xh, wh, acc[et], 0, 0, 0);
            acc[et] = __builtin_amdgcn_mfma_f32_16x16x32_bf16(xh, wl, acc[et], 0, 0, 0);
            acc[et] = __builtin_amdgcn_mfma_f32_16x16x32_bf16(xh, wq, acc[et], 0, 0, 0);
            acc[et] = __builtin_amdgcn_mfma_f32_16x16x32_bf16(xl, wh, acc[et], 0, 0, 0);
            acc[et] = __builtin_amdgcn_mfma_f32_16x16x32_bf16(xl, wl, acc[et], 0, 0, 0);
            acc[et] = __builtin_amdgcn_mfma_f32_16x16x32_bf16(xq, wh, acc[et], 0, 0, 0);
        }
    }

    // epilogue: C/D map col=lane&15 (expert), row=(lane>>4)*4+i (token)
    float* Pp = P + (size_t)slice * T_TOKENS * NEXP;
#pragma unroll
    for (int et = 0; et < 4; ++et) {
#pragma unroll
        for (int i = 0; i < 4; ++i) {
            int t = t0 + wv * 16 + (l >> 4) * 4 + i;
            Pp[(size_t)t * NEXP + et * 16 + (l & 15)] = acc[et][i];
        }
    }
}

// ---------- kernel 2: reduce slices + softmax + argmax + bincount ------------
__global__ __launch_bounds__(256) void router_finish(
    const float* __restrict__ P, float* __restrict__ out, int S)
{
    const int lane = threadIdx.x & 63;   // expert
    const int wv   = threadIdx.x >> 6;
    const int t    = blockIdx.x * 4 + wv;

    float lg = 0.f;
    for (int s = 0; s < S; ++s)
        lg += P[((size_t)s * T_TOKENS + t) * NEXP + lane];

    float* out_w = out;
    float* out_i = out + T_TOKENS;
    float* out_s = out + 2 * T_TOKENS;
    float* out_c = out + 2 * T_TOKENS + (size_t)T_TOKENS * NEXP;

    float m = lg;
#pragma unroll
    for (int off = 32; off > 0; off >>= 1)
        m = fmaxf(m, __shfl_xor(m, off));
    float p = expf(lg - m);
    float s = p;
#pragma unroll
    for (int off = 32; off > 0; off >>= 1)
        s += __shfl_xor(s, off);
    float sc = p / s;

    float bv = sc; int bi = lane;
#pragma unroll
    for (int off = 32; off > 0; off >>= 1) {
        float ov = __shfl_xor(bv, off);
        int   oi = __shfl_xor(bi, off);
        if (ov > bv || (ov == bv && oi < bi)) { bv = ov; bi = oi; }
    }
    out_s[(size_t)t * NEXP + lane] = sc;
    if (lane == 0) {
        out_w[t] = bv;
        out_i[t] = (float)bi;
        atomicAdd(&out_c[bi], 1.0f);   // counts zeroed by wpack this call
    }
}

extern "C" void kernel_launch(void* const* d_in, const int* in_sizes, int n_in,
                              void* d_out, int out_size, void* d_ws, size_t ws_size,
                              hipStream_t stream)
{
    const float* x = (const float*)d_in[0];
    const float* W = (const float*)d_in[1];
    float* out = (float*)d_out;
    float* out_s = out + 2 * T_TOKENS;
    float* out_c = out + 2 * T_TOKENS + (size_t)T_TOKENS * NEXP;

    const size_t wf_bytes  = (size_t)128 * 4 * 3 * 64 * 16;           // 1.5 MiB
    const size_t per_slice = (size_t)T_TOKENS * NEXP * sizeof(float); // 2 MiB

    int S = 8;
    while (S > 1 && wf_bytes + (size_t)S * per_slice > ws_size) S >>= 1;
    float4* Wf = (float4*)d_ws;
    float* Pbuf;
    if (wf_bytes + per_slice <= ws_size) {
        Pbuf = (float*)((char*)d_ws + wf_bytes);
    } else {
        S = 1;
        Pbuf = out_s;   // single slice written straight into scores region
    }

    // NO hipMemsetAsync: counts are zeroed by wpack (stream-ordered).
    wpack<<<dim3(128, 4), 64, 0, stream>>>(W, Wf, out_c);
    gemm_mfma<<<dim3(T_TOKENS / TB, S), 512, 0, stream>>>(x, Wf, Pbuf, K_DIM / S);
    router_finish<<<T_TOKENS / 4, 256, 0, stream>>>(Pbuf, out, S);
}

// Round 6
// 94.607 us; speedup vs baseline: 1.1088x; 1.0016x over previous
//
#include <hip/hip_runtime.h>
#include <stdint.h>

#define T_TOKENS 8192
#define K_DIM    4096
#define NEXP     64
#define TB       128            // tokens per gemm block (8 waves x 16)
#define KC       64             // k per chunk = 2 MFMA k-steps

typedef short bf16x8 __attribute__((ext_vector_type(8)));
typedef float f32x4  __attribute__((ext_vector_type(4)));

// float -> bf16 (RNE) bit tricks; residual v - bf2f(f2bf(v)) is exact in fp32
__device__ __forceinline__ uint32_t f2bf(float v) {
    uint32_t u = __builtin_bit_cast(uint32_t, v);
    return (u + 0x7fffu + ((u >> 16) & 1u)) >> 16;
}
__device__ __forceinline__ float bf2f(uint32_t b) {
    return __builtin_bit_cast(float, b << 16);
}

// 8 fp32 -> 3-term bf16 split (xh + xl + xq, residual chain exact in fp32)
__device__ __forceinline__ void cvt3(const float4 a0, const float4 a1,
                                     bf16x8& xh, bf16x8& xl, bf16x8& xq) {
    const float av[8] = {a0.x, a0.y, a0.z, a0.w, a1.x, a1.y, a1.z, a1.w};
#pragma unroll
    for (int j = 0; j < 8; ++j) {
        float v = av[j];
        uint32_t hb = f2bf(v); float r  = v - bf2f(hb);
        uint32_t lb = f2bf(r); float r2 = r - bf2f(lb);
        uint32_t qb = f2bf(r2);
        xh[j] = (short)hb; xl[j] = (short)lb; xq[j] = (short)qb;
    }
}

// ---------- kernel 0: W [64][4096] fp32 -> fragment-ordered bf16 terms -------
// Wf layout (float4 = bf16x8 units): [kstep 128][etile 4][term 3][lane 64]
// B-frag content: lane l, elem j = W[etile*16 + (l&15)][kstep*32 + (l>>4)*8 + j]
// Block (0,0) also zeroes the routing-counts output (replaces graph memset).
__global__ void wpack(const float* __restrict__ W, float4* __restrict__ Wf,
                      float* __restrict__ out_counts) {
    const int l     = threadIdx.x;       // 0..63
    const int kstep = blockIdx.x;        // 0..127
    const int etile = blockIdx.y;        // 0..3
    if (kstep == 0 && etile == 0)
        out_counts[l] = 0.f;             // stream-ordered before router_finish
    const int e = etile * 16 + (l & 15);
    const int k = kstep * 32 + (l >> 4) * 8;
    const float* src = W + (size_t)e * K_DIM + k;
    bf16x8 h, l1, l2;
#pragma unroll
    for (int j = 0; j < 8; ++j) {
        float v = src[j];
        uint32_t hb = f2bf(v); float r  = v - bf2f(hb);
        uint32_t lb = f2bf(r); float r2 = r - bf2f(lb);
        uint32_t qb = f2bf(r2);
        h[j] = (short)hb; l1[j] = (short)lb; l2[j] = (short)qb;
    }
    const size_t base = ((size_t)(kstep * 4 + etile) * 3) * 64 + l;
    Wf[base]       = __builtin_bit_cast(float4, h);
    Wf[base + 64]  = __builtin_bit_cast(float4, l1);
    Wf[base + 128] = __builtin_bit_cast(float4, l2);
}

// ---------- kernel 1: split-K GEMM, logits partials via 6x bf16 MFMA ---------
// x: DIRECT global->register A-fragments (zero cross-wave reuse -> no LDS),
//    prefetched one chunk ahead; per-lane 32 B contiguous = full-line coalesce.
// B: LDS double-buffer (8-way shared), 24 KB/chunk, linear layout, ONE barrier
//    per chunk (dbuf WAR spans two barriers). nchunk=8 barriers total.
__global__ __launch_bounds__(512, 4) void gemm_mfma(
    const float*  __restrict__ x,
    const float4* __restrict__ Wf,
    float* __restrict__ P,          // [S][8192][64]
    int KS)                         // k per slice
{
    __shared__ float4 bbuf[2][1536];     // [kstep 2][etile 4][term 3][lane 64] x2 = 48 KB

    const int tid  = threadIdx.x;
    const int l    = tid & 63;
    const int wv   = __builtin_amdgcn_readfirstlane(tid >> 6);  // token-16 tile
    const int t0   = blockIdx.x * TB;
    const int slice = blockIdx.y;
    const int k0   = slice * KS;
    const int nchunk = KS / KC;

    // per-lane A-fragment source: x[t0+arow][k0 + c*64 + ks*32 + (l>>4)*8 + 0..7]
    const float4* x4 = (const float4*)x;
    const int arow = wv * 16 + (l & 15);
    const size_t xg = (size_t)(t0 + arow) * (K_DIM / 4) + (size_t)(k0 >> 2) + ((l >> 4) * 2);

    // B chunk base (f4 units): kstep size 768, chunk = 2 ksteps = 1536
    const size_t bg0 = ((size_t)(k0 >> 5)) * 768;

    f32x4 acc[4];
#pragma unroll
    for (int et = 0; et < 4; ++et) acc[et] = (f32x4){0.f, 0.f, 0.f, 0.f};

    // prologue: chunk-0 B regs + chunk-0 x fragments
    float4 br0 = Wf[bg0 + tid];
    float4 br1 = Wf[bg0 + tid + 512];
    float4 br2 = Wf[bg0 + tid + 1024];
    float4 xa0 = x4[xg + 0], xa1 = x4[xg + 1];   // kstep 0
    float4 xa2 = x4[xg + 8], xa3 = x4[xg + 9];   // kstep 1

    for (int c = 0; c < nchunk; ++c) {
        const int b = c & 1;
        // commit B chunk c (lane-consecutive b128 writes, conflict-free)
        bbuf[b][tid]        = br0;
        bbuf[b][tid + 512]  = br1;
        bbuf[b][tid + 1024] = br2;
        __syncthreads();   // only barrier: WAR on buf b is 2 barriers out

        // prefetch chunk c+1 (B -> regs for next commit, x -> next A-frags);
        // latency hides under this chunk's convert + 48 MFMAs
        float4 xn0 = xa0, xn1 = xa1, xn2 = xa2, xn3 = xa3;
        if (c + 1 < nchunk) {
            const size_t bo = bg0 + (size_t)(c + 1) * 1536;
            br0 = Wf[bo + tid];
            br1 = Wf[bo + tid + 512];
            br2 = Wf[bo + tid + 1024];
            const size_t xo = xg + (size_t)(c + 1) * 16;
            xn0 = x4[xo + 0]; xn1 = x4[xo + 1];
            xn2 = x4[xo + 8]; xn3 = x4[xo + 9];
        }

        // A fragments: 16 fp32 -> 3 bf16 terms per kstep
        bf16x8 xh0, xl0, xq0, xh1, xl1, xq1;
        cvt3(xa0, xa1, xh0, xl0, xq0);
        cvt3(xa2, xa3, xh1, xl1, xq1);

#pragma unroll
        for (int et = 0; et < 4; ++et) {
            {   // kstep 0 of chunk (global k order identical to R5)
                const float4* bp = &bbuf[b][et * 192 + l];
                bf16x8 wh = __builtin_bit_cast(bf16x8, bp[0]);
                bf16x8 wl = __builtin_bit_cast(bf16x8, bp[64]);
                bf16x8 wq = __builtin_bit_cast(bf16x8, bp[128]);
                acc[et] = __builtin_amdgcn_mfma_f32_16x16x32_bf16(xh0, wh, acc[et], 0, 0, 0);
                acc[et] = __builtin_amdgcn_mfma_f32_16x16x32_bf16(xh0, wl, acc[et], 0, 0, 0);
                acc[et] = __builtin_amdgcn_mfma_f32_16x16x32_bf16(xh0, wq, acc[et], 0, 0, 0);
                acc[et] = __builtin_amdgcn_mfma_f32_16x16x32_bf16(xl0, wh, acc[et], 0, 0, 0);
                acc[et] = __builtin_amdgcn_mfma_f32_16x16x32_bf16(xl0, wl, acc[et], 0, 0, 0);
                acc[et] = __builtin_amdgcn_mfma_f32_16x16x32_bf16(xq0, wh, acc[et], 0, 0, 0);
            }
            {   // kstep 1
                const float4* bp = &bbuf[b][768 + et * 192 + l];
                bf16x8 wh = __builtin_bit_cast(bf16x8, bp[0]);
                bf16x8 wl = __builtin_bit_cast(bf16x8, bp[64]);
                bf16x8 wq = __builtin_bit_cast(bf16x8, bp[128]);
                acc[et] = __builtin_amdgcn_mfma_f32_16x16x32_bf16(xh1, wh, acc[et], 0, 0, 0);
                acc[et] = __builtin_amdgcn_mfma_f32_16x16x32_bf16(xh1, wl, acc[et], 0, 0, 0);
                acc[et] = __builtin_amdgcn_mfma_f32_16x16x32_bf16(xh1, wq, acc[et], 0, 0, 0);
                acc[et] = __builtin_amdgcn_mfma_f32_16x16x32_bf16(xl1, wh, acc[et], 0, 0, 0);
                acc[et] = __builtin_amdgcn_mfma_f32_16x16x32_bf16(xl1, wl, acc[et], 0, 0, 0);
                acc[et] = __builtin_amdgcn_mfma_f32_16x16x32_bf16(xq1, wh, acc[et], 0, 0, 0);
            }
        }
        xa0 = xn0; xa1 = xn1; xa2 = xn2; xa3 = xn3;
    }

    // epilogue: C/D map col=lane&15 (expert), row=(lane>>4)*4+i (token)
    float* Pp = P + (size_t)slice * T_TOKENS * NEXP;
#pragma unroll
    for (int et = 0; et < 4; ++et) {
#pragma unroll
        for (int i = 0; i < 4; ++i) {
            int t = t0 + wv * 16 + (l >> 4) * 4 + i;
            Pp[(size_t)t * NEXP + et * 16 + (l & 15)] = acc[et][i];
        }
    }
}

// ---------- kernel 2: reduce slices + softmax + argmax + bincount ------------
template <int S>
__global__ __launch_bounds__(256) void router_finish_t(
    const float* __restrict__ P, float* __restrict__ out)
{
    const int lane = threadIdx.x & 63;   // expert
    const int wv   = threadIdx.x >> 6;
    const int t    = blockIdx.x * 4 + wv;

    float lg = 0.f;
#pragma unroll
    for (int s = 0; s < S; ++s)
        lg += P[((size_t)s * T_TOKENS + t) * NEXP + lane];

    float* out_w = out;
    float* out_i = out + T_TOKENS;
    float* out_s = out + 2 * T_TOKENS;
    float* out_c = out + 2 * T_TOKENS + (size_t)T_TOKENS * NEXP;

    float m = lg;
#pragma unroll
    for (int off = 32; off > 0; off >>= 1)
        m = fmaxf(m, __shfl_xor(m, off));
    float p = expf(lg - m);
    float s = p;
#pragma unroll
    for (int off = 32; off > 0; off >>= 1)
        s += __shfl_xor(s, off);
    float sc = p / s;

    float bv = sc; int bi = lane;
#pragma unroll
    for (int off = 32; off > 0; off >>= 1) {
        float ov = __shfl_xor(bv, off);
        int   oi = __shfl_xor(bi, off);
        if (ov > bv || (ov == bv && oi < bi)) { bv = ov; bi = oi; }
    }
    out_s[(size_t)t * NEXP + lane] = sc;
    if (lane == 0) {
        out_w[t] = bv;
        out_i[t] = (float)bi;
        atomicAdd(&out_c[bi], 1.0f);   // counts zeroed by wpack this call
    }
}

extern "C" void kernel_launch(void* const* d_in, const int* in_sizes, int n_in,
                              void* d_out, int out_size, void* d_ws, size_t ws_size,
                              hipStream_t stream)
{
    const float* x = (const float*)d_in[0];
    const float* W = (const float*)d_in[1];
    float* out = (float*)d_out;
    float* out_s = out + 2 * T_TOKENS;
    float* out_c = out + 2 * T_TOKENS + (size_t)T_TOKENS * NEXP;

    const size_t wf_bytes  = (size_t)128 * 4 * 3 * 64 * 16;           // 1.5 MiB
    const size_t per_slice = (size_t)T_TOKENS * NEXP * sizeof(float); // 2 MiB

    int S = 8;
    while (S > 1 && wf_bytes + (size_t)S * per_slice > ws_size) S >>= 1;
    float4* Wf = (float4*)d_ws;
    float* Pbuf;
    if (wf_bytes + per_slice <= ws_size) {
        Pbuf = (float*)((char*)d_ws + wf_bytes);
    } else {
        S = 1;
        Pbuf = out_s;   // single slice written straight into scores region
    }

    wpack<<<dim3(128, 4), 64, 0, stream>>>(W, Wf, out_c);
    gemm_mfma<<<dim3(T_TOKENS / TB, S), 512, 0, stream>>>(x, Wf, Pbuf, K_DIM / S);
    switch (S) {
        case 8: router_finish_t<8><<<T_TOKENS / 4, 256, 0, stream>>>(Pbuf, out); break;
        case 4: router_finish_t<4><<<T_TOKENS / 4, 256, 0, stream>>>(Pbuf, out); break;
        case 2: router_finish_t<2><<<T_TOKENS / 4, 256, 0, stream>>>(Pbuf, out); break;
        default: router_finish_t<1><<<T_TOKENS / 4, 256, 0, stream>>>(Pbuf, out); break;
    }
}

// Round 8
// 93.627 us; speedup vs baseline: 1.1204x; 1.0105x over previous
//
#include <hip/hip_runtime.h>
#include <stdint.h>

#define T_TOKENS 8192
#define K_DIM    4096
#define NEXP     64
#define TB       128            // tokens per gemm block (8 waves x 16)
#define KC       64             // k per chunk = 2 MFMA k-steps

typedef short bf16x8 __attribute__((ext_vector_type(8)));
typedef float f32x4  __attribute__((ext_vector_type(4)));

// float -> bf16 (RNE) bit tricks; residual v - bf2f(f2bf(v)) is exact in fp32
__device__ __forceinline__ uint32_t f2bf(float v) {
    uint32_t u = __builtin_bit_cast(uint32_t, v);
    return (u + 0x7fffu + ((u >> 16) & 1u)) >> 16;
}
__device__ __forceinline__ float bf2f(uint32_t b) {
    return __builtin_bit_cast(float, b << 16);
}
struct S3 { short h, l, q; };
__device__ __forceinline__ S3 cvt1(float v) {
    uint32_t hb = f2bf(v); float r  = v - bf2f(hb);
    uint32_t lb = f2bf(r); float r2 = r - bf2f(lb);
    uint32_t qb = f2bf(r2);
    S3 o; o.h = (short)hb; o.l = (short)lb; o.q = (short)qb; return o;
}
__device__ __forceinline__ void cvt8(const float4 a0, const float4 a1,
                                     bf16x8& xh, bf16x8& xl, bf16x8& xq) {
    const float av[8] = {a0.x, a0.y, a0.z, a0.w, a1.x, a1.y, a1.z, a1.w};
#pragma unroll
    for (int j = 0; j < 8; ++j) {
        S3 o = cvt1(av[j]);
        xh[j] = o.h; xl[j] = o.l; xq[j] = o.q;
    }
}

// ---------- kernel 0: W [64][4096] fp32 -> fragment-ordered bf16 terms -------
// Wf layout (float4 = bf16x8 units): [kstep 128][etile 4][term 3][lane 64]
// B-frag content: lane l, elem j = W[etile*16 + (l&15)][kstep*32 + (l>>4)*8 + j]
__global__ void wpack(const float* __restrict__ W, float4* __restrict__ Wf,
                      float* __restrict__ out_counts) {
    const int l     = threadIdx.x;       // 0..63
    const int kstep = blockIdx.x;        // 0..127
    const int etile = blockIdx.y;        // 0..3
    if (kstep == 0 && etile == 0)
        out_counts[l] = 0.f;             // stream-ordered before router_finish
    const int e = etile * 16 + (l & 15);
    const int k = kstep * 32 + (l >> 4) * 8;
    const float* src = W + (size_t)e * K_DIM + k;
    bf16x8 h, l1, l2;
#pragma unroll
    for (int j = 0; j < 8; ++j) {
        S3 o = cvt1(src[j]);
        h[j] = o.h; l1[j] = o.l; l2[j] = o.q;
    }
    const size_t base = ((size_t)(kstep * 4 + etile) * 3) * 64 + l;
    Wf[base]       = __builtin_bit_cast(float4, h);
    Wf[base + 64]  = __builtin_bit_cast(float4, l1);
    Wf[base + 128] = __builtin_bit_cast(float4, l2);
}

// ---------- kernel 1: split-K GEMM, logits partials via 6x bf16 MFMA ---------
// x: direct global->register A-fragments (no cross-wave reuse), double-set
//    prefetch one chunk ahead. B: global_load_lds width-16 straight L2->LDS
//    (zero staging VGPRs, no commit phase), linear lane-ordered layout.
//    ONE barrier + one vmcnt(0) per chunk. Live VGPRs ~90 < 128 (no spill).
__global__ __launch_bounds__(512, 4) void gemm_mfma(
    const float*  __restrict__ x,
    const float4* __restrict__ Wf,
    float* __restrict__ P,          // [S][8192][64]
    int KS)                         // k per slice
{
    __shared__ float4 bbuf[2][1536];     // [kstep 2][etile 4][term 3][lane 64] x2 = 48 KB

    const int tid  = threadIdx.x;
    const int l    = tid & 63;
    const int wv   = __builtin_amdgcn_readfirstlane(tid >> 6);  // token-16 tile
    const int t0   = blockIdx.x * TB;
    const int slice = blockIdx.y;
    const int k0   = slice * KS;
    const int nchunk = KS / KC;

    // per-lane A-fragment source: x[t0+arow][k0 + c*64 + ks*32 + (l>>4)*8 + 0..7]
    const float4* x4 = (const float4*)x;
    const int arow = wv * 16 + (l & 15);
    const size_t xg = (size_t)(t0 + arow) * (K_DIM / 4) + (size_t)(k0 >> 2) + ((l >> 4) * 2);

    // B chunk base (f4 units): kstep = 768 f4, chunk = 2 ksteps = 1536 f4 = 24 KB
    const size_t bg0 = ((size_t)(k0 >> 5)) * 768;

    f32x4 acc[4];
#pragma unroll
    for (int et = 0; et < 4; ++et) acc[et] = (f32x4){0.f, 0.f, 0.f, 0.f};

    // prologue: B chunk 0 via glds; x chunk 0 to regs
#pragma unroll
    for (int q = 0; q < 3; ++q)
        __builtin_amdgcn_global_load_lds(
            (const __attribute__((address_space(1))) void*)(Wf + bg0 + (wv * 3 + q) * 64 + l),
            (__attribute__((address_space(3))) void*)&bbuf[0][(wv * 3 + q) * 64],
            16, 0, 0);
    float4 xa0 = x4[xg + 0], xa1 = x4[xg + 1];   // kstep 0
    float4 xa2 = x4[xg + 8], xa3 = x4[xg + 9];   // kstep 1
    asm volatile("s_waitcnt vmcnt(0)" ::: "memory");
    __syncthreads();

    for (int c = 0; c < nchunk; ++c) {
        const int b  = c & 1;
        const int nb = b ^ 1;

        // issue next chunk's B (L2->LDS, no regs) and x loads FIRST;
        // their latency hides under this chunk's convert + 48 MFMAs.
        float4 xn0 = xa0, xn1 = xa1, xn2 = xa2, xn3 = xa3;
        if (c + 1 < nchunk) {
            const size_t bo = bg0 + (size_t)(c + 1) * 1536;
#pragma unroll
            for (int q = 0; q < 3; ++q)
                __builtin_amdgcn_global_load_lds(
                    (const __attribute__((address_space(1))) void*)(Wf + bo + (wv * 3 + q) * 64 + l),
                    (__attribute__((address_space(3))) void*)&bbuf[nb][(wv * 3 + q) * 64],
                    16, 0, 0);
            const size_t xo = xg + (size_t)(c + 1) * 16;
            xn0 = x4[xo + 0]; xn1 = x4[xo + 1];
            xn2 = x4[xo + 8]; xn3 = x4[xo + 9];
        }

        // A fragments: 16 fp32 -> 3 bf16 terms per kstep (identical math to R6)
        bf16x8 xh0, xl0, xq0, xh1, xl1, xq1;
        cvt8(xa0, xa1, xh0, xl0, xq0);
        cvt8(xa2, xa3, xh1, xl1, xq1);

#pragma unroll
        for (int et = 0; et < 4; ++et) {
            {   // kstep 0
                const float4* bp = &bbuf[b][et * 192 + l];
                bf16x8 wh = __builtin_bit_cast(bf16x8, bp[0]);
                bf16x8 wl = __builtin_bit_cast(bf16x8, bp[64]);
                bf16x8 wq = __builtin_bit_cast(bf16x8, bp[128]);
                acc[et] = __builtin_amdgcn_mfma_f32_16x16x32_bf16(xh0, wh, acc[et], 0, 0, 0);
                acc[et] = __builtin_amdgcn_mfma_f32_16x16x32_bf16(xh0, wl, acc[et], 0, 0, 0);
                acc[et] = __builtin_amdgcn_mfma_f32_16x16x32_bf16(xh0, wq, acc[et], 0, 0, 0);
                acc[et] = __builtin_amdgcn_mfma_f32_16x16x32_bf16(xl0, wh, acc[et], 0, 0, 0);
                acc[et] = __builtin_amdgcn_mfma_f32_16x16x32_bf16(xl0, wl, acc[et], 0, 0, 0);
                acc[et] = __builtin_amdgcn_mfma_f32_16x16x32_bf16(xq0, wh, acc[et], 0, 0, 0);
            }
            {   // kstep 1
                const float4* bp = &bbuf[b][768 + et * 192 + l];
                bf16x8 wh = __builtin_bit_cast(bf16x8, bp[0]);
                bf16x8 wl = __builtin_bit_cast(bf16x8, bp[64]);
                bf16x8 wq = __builtin_bit_cast(bf16x8, bp[128]);
                acc[et] = __builtin_amdgcn_mfma_f32_16x16x32_bf16(xh1, wh, acc[et], 0, 0, 0);
                acc[et] = __builtin_amdgcn_mfma_f32_16x16x32_bf16(xh1, wl, acc[et], 0, 0, 0);
                acc[et] = __builtin_amdgcn_mfma_f32_16x16x32_bf16(xh1, wq, acc[et], 0, 0, 0);
                acc[et] = __builtin_amdgcn_mfma_f32_16x16x32_bf16(xl1, wh, acc[et], 0, 0, 0);
                acc[et] = __builtin_amdgcn_mfma_f32_16x16x32_bf16(xl1, wl, acc[et], 0, 0, 0);
                acc[et] = __builtin_amdgcn_mfma_f32_16x16x32_bf16(xq1, wh, acc[et], 0, 0, 0);
            }
        }

        asm volatile("s_waitcnt vmcnt(0)" ::: "memory");  // next B in LDS, xn in regs
        __syncthreads();
        xa0 = xn0; xa1 = xn1; xa2 = xn2; xa3 = xn3;
    }

    // epilogue: C/D map col=lane&15 (expert), row=(lane>>4)*4+i (token)
    float* Pp = P + (size_t)slice * T_TOKENS * NEXP;
#pragma unroll
    for (int et = 0; et < 4; ++et) {
#pragma unroll
        for (int i = 0; i < 4; ++i) {
            int t = t0 + wv * 16 + (l >> 4) * 4 + i;
            Pp[(size_t)t * NEXP + et * 16 + (l & 15)] = acc[et][i];
        }
    }
}

// ---------- kernel 2: reduce slices + softmax + argmax + bincount ------------
template <int S>
__global__ __launch_bounds__(256) void router_finish_t(
    const float* __restrict__ P, float* __restrict__ out)
{
    const int lane = threadIdx.x & 63;   // expert
    const int wv   = threadIdx.x >> 6;
    const int t    = blockIdx.x * 4 + wv;

    float lg = 0.f;
#pragma unroll
    for (int s = 0; s < S; ++s)
        lg += P[((size_t)s * T_TOKENS + t) * NEXP + lane];

    float* out_w = out;
    float* out_i = out + T_TOKENS;
    float* out_s = out + 2 * T_TOKENS;
    float* out_c = out + 2 * T_TOKENS + (size_t)T_TOKENS * NEXP;

    float m = lg;
#pragma unroll
    for (int off = 32; off > 0; off >>= 1)
        m = fmaxf(m, __shfl_xor(m, off));
    float p = expf(lg - m);
    float s = p;
#pragma unroll
    for (int off = 32; off > 0; off >>= 1)
        s += __shfl_xor(s, off);
    float sc = p / s;

    float bv = sc; int bi = lane;
#pragma unroll
    for (int off = 32; off > 0; off >>= 1) {
        float ov = __shfl_xor(bv, off);
        int   oi = __shfl_xor(bi, off);
        if (ov > bv || (ov == bv && oi < bi)) { bv = ov; bi = oi; }
    }
    out_s[(size_t)t * NEXP + lane] = sc;
    if (lane == 0) {
        out_w[t] = bv;
        out_i[t] = (float)bi;
        atomicAdd(&out_c[bi], 1.0f);   // counts zeroed by wpack this call
    }
}

extern "C" void kernel_launch(void* const* d_in, const int* in_sizes, int n_in,
                              void* d_out, int out_size, void* d_ws, size_t ws_size,
                              hipStream_t stream)
{
    const float* x = (const float*)d_in[0];
    const float* W = (const float*)d_in[1];
    float* out = (float*)d_out;
    float* out_s = out + 2 * T_TOKENS;
    float* out_c = out + 2 * T_TOKENS + (size_t)T_TOKENS * NEXP;

    const size_t wf_bytes  = (size_t)128 * 4 * 3 * 64 * 16;           // 1.5 MiB
    const size_t per_slice = (size_t)T_TOKENS * NEXP * sizeof(float); // 2 MiB

    int S = 8;
    while (S > 1 && wf_bytes + (size_t)S * per_slice > ws_size) S >>= 1;
    float4* Wf = (float4*)d_ws;
    float* Pbuf;
    if (wf_bytes + per_slice <= ws_size) {
        Pbuf = (float*)((char*)d_ws + wf_bytes);
    } else {
        S = 1;
        Pbuf = out_s;   // single slice written straight into scores region
    }

    wpack<<<dim3(128, 4), 64, 0, stream>>>(W, Wf, out_c);
    gemm_mfma<<<dim3(T_TOKENS / TB, S), 512, 0, stream>>>(x, Wf, Pbuf, K_DIM / S);
    switch (S) {
        case 8: router_finish_t<8><<<T_TOKENS / 4, 256, 0, stream>>>(Pbuf, out); break;
        case 4: router_finish_t<4><<<T_TOKENS / 4, 256, 0, stream>>>(Pbuf, out); break;
        case 2: router_finish_t<2><<<T_TOKENS / 4, 256, 0, stream>>>(Pbuf, out); break;
        default: router_finish_t<1><<<T_TOKENS / 4, 256, 0, stream>>>(Pbuf, out); break;
    }
}